// Round 3
// baseline (184.727 us; speedup 1.0000x reference)
//
#include <hip/hip_runtime.h>
#include <hip/hip_bf16.h>

// LBONorm: fused LayerNorm + low-rank diffusion smoothing.
// rows = B*S = 16384, d = 2048 (fp32), rank = 8.
// Block = 256 thr (4 waves) owns 8 rows; thread t owns cols {4t..4t+3, 1024+4t..+3}.
// V register-resident (64 VGPR), amortized over 8 rows.
// R1 lesson: launch_bounds cap < need -> spill (FETCH 606MB). Need ~150 -> (256,3).
// R2 lesson: latency-bound at 2.2 TB/s (VALUBusy 26%): too few bytes in flight,
//   2 barriers/row. Fix: batch 2 rows/phase (22-value butterfly incl. deferred
//   e-partials), prefetch next pair a full phase ahead.

constexpr int D       = 2048;
constexpr int RANK    = 8;
constexpr int BLOCK   = 256;
constexpr int ROWS_PB = 8;
constexpr int NPH     = 4;      // phases per block, 2 rows each
constexpr float LN_EPS = 1e-5f;

__device__ __forceinline__ float wred(float v) {
    #pragma unroll
    for (int off = 32; off > 0; off >>= 1) v += __shfl_xor(v, off, 64);
    return v;
}

__global__ __launch_bounds__(BLOCK, 3)
void lbonorm_kernel(const float* __restrict__ h,
                    const float* __restrict__ gamma,
                    const float* __restrict__ beta,
                    const float* __restrict__ V,
                    const float* __restrict__ eta_p,
                    float* __restrict__ out,
                    float* __restrict__ e_out)
{
    const int t    = threadIdx.x;
    const int lane = t & 63;
    const int wave = t >> 6;

    const int c0 = t * 4;
    const int c1 = D / 2 + t * 4;

    // red[n][w]: per-wave partial of value n (20 stats + 2 prev-pair e)
    __shared__ __align__(16) float red[22][4];

    const size_t row0 = (size_t)blockIdx.x * ROWS_PB;

    // ---- issue first-pair h loads ASAP (overlap with V setup)
    float4 hA[2][2];
    hA[0][0] = *reinterpret_cast<const float4*>(h + row0 * (size_t)D + c0);
    hA[0][1] = *reinterpret_cast<const float4*>(h + row0 * (size_t)D + c1);
    hA[1][0] = *reinterpret_cast<const float4*>(h + (row0 + 1) * (size_t)D + c0);
    hA[1][1] = *reinterpret_cast<const float4*>(h + (row0 + 1) * (size_t)D + c1);

    // ---- V columns into registers: vreg[k][r] = V[r][col_k]
    float vreg[8][RANK];
    #pragma unroll
    for (int r = 0; r < RANK; ++r) {
        float4 a = *reinterpret_cast<const float4*>(V + (size_t)r * D + c0);
        float4 b = *reinterpret_cast<const float4*>(V + (size_t)r * D + c1);
        vreg[0][r] = a.x; vreg[1][r] = a.y; vreg[2][r] = a.z; vreg[3][r] = a.w;
        vreg[4][r] = b.x; vreg[5][r] = b.y; vreg[6][r] = b.z; vreg[7][r] = b.w;
    }

    const float4 g0 = *reinterpret_cast<const float4*>(gamma + c0);
    const float4 g1 = *reinterpret_cast<const float4*>(gamma + c1);
    const float4 bb0 = *reinterpret_cast<const float4*>(beta + c0);
    const float4 bb1 = *reinterpret_cast<const float4*>(beta + c1);
    const float gam[8] = {g0.x,g0.y,g0.z,g0.w,g1.x,g1.y,g1.z,g1.w};
    const float bet[8] = {bb0.x,bb0.y,bb0.z,bb0.w,bb1.x,bb1.y,bb1.z,bb1.w};
    const float eta = fminf(fmaxf(eta_p[0], 0.0f), 0.5f);

    // ---- per-rank column sums of V -> registers (all threads)
    float vsum[RANK];
    {
        float vs[RANK];
        #pragma unroll
        for (int r = 0; r < RANK; ++r) {
            vs[r] = 0.f;
            #pragma unroll
            for (int k = 0; k < 8; ++k) vs[r] += vreg[k][r];
            vs[r] = wred(vs[r]);
        }
        if (lane == 0) {
            #pragma unroll
            for (int r = 0; r < RANK; ++r) red[r][wave] = vs[r];
        }
        __syncthreads();
        #pragma unroll
        for (int r = 0; r < RANK; ++r) {
            float4 q = *reinterpret_cast<const float4*>(red[r]);
            vsum[r] = (q.x + q.y) + (q.z + q.w);
        }
        // phase-0 barrier A protects red[] before it's overwritten
    }

    float ep[2] = {0.f, 0.f};   // e_curv partials of the PREVIOUS pair

    for (int p = 0; p < NPH; ++p) {
        // ---- prefetch next pair a full phase ahead
        float4 hN[2][2];
        if (p + 1 < NPH) {
            const size_t r2 = row0 + 2 * (p + 1);
            hN[0][0] = *reinterpret_cast<const float4*>(h + r2 * (size_t)D + c0);
            hN[0][1] = *reinterpret_cast<const float4*>(h + r2 * (size_t)D + c1);
            hN[1][0] = *reinterpret_cast<const float4*>(h + (r2 + 1) * (size_t)D + c0);
            hN[1][1] = *reinterpret_cast<const float4*>(h + (r2 + 1) * (size_t)D + c1);
        }

        // ---- partials: per row {s, s2, dot[0..7]} + prev-pair e partials
        float vals[22];
        #pragma unroll
        for (int b = 0; b < 2; ++b) {
            const float hb[8] = {hA[b][0].x, hA[b][0].y, hA[b][0].z, hA[b][0].w,
                                 hA[b][1].x, hA[b][1].y, hA[b][1].z, hA[b][1].w};
            float s = 0.f, s2 = 0.f;
            #pragma unroll
            for (int k = 0; k < 8; ++k) { s += hb[k]; s2 = fmaf(hb[k], hb[k], s2); }
            vals[b * 10]     = s;
            vals[b * 10 + 1] = s2;
            #pragma unroll
            for (int r = 0; r < RANK; ++r) {
                float dp = 0.f;
                #pragma unroll
                for (int k = 0; k < 8; ++k) dp = fmaf(hb[k], vreg[k][r], dp);
                vals[b * 10 + 2 + r] = dp;
            }
        }
        vals[20] = ep[0];
        vals[21] = ep[1];
        #pragma unroll
        for (int n = 0; n < 22; ++n) vals[n] = wred(vals[n]);

        __syncthreads();                       // A: prev-phase red[] reads done
        if (lane == 0) {
            #pragma unroll
            for (int n = 0; n < 22; ++n) red[n][wave] = vals[n];
        }
        __syncthreads();                       // B: partials visible

        float tot[22];
        #pragma unroll
        for (int n = 0; n < 22; ++n) {
            float4 q = *reinterpret_cast<const float4*>(red[n]);
            tot[n] = (q.x + q.y) + (q.z + q.w);
        }

        if (t == 0 && p > 0) {                 // previous pair's e_curv
            e_out[row0 + 2 * p - 2] = tot[20];
            e_out[row0 + 2 * p - 1] = tot[21];
        }

        // ---- epilogue for both rows of the pair
        #pragma unroll
        for (int b = 0; b < 2; ++b) {
            const float mu  = tot[b * 10] * (1.0f / D);
            const float var = fmaxf(tot[b * 10 + 1] * (1.0f / D) - mu * mu, 0.0f);
            const float inv = rsqrtf(var + LN_EPS);
            float c[RANK];
            #pragma unroll
            for (int r = 0; r < RANK; ++r)
                c[r] = inv * (tot[b * 10 + 2 + r] - mu * vsum[r]);

            const float hb[8] = {hA[b][0].x, hA[b][0].y, hA[b][0].z, hA[b][0].w,
                                 hA[b][1].x, hA[b][1].y, hA[b][1].z, hA[b][1].w};
            float e = 0.f, ov[8];
            #pragma unroll
            for (int k = 0; k < 8; ++k) {
                const float hh = (hb[k] - mu) * inv;
                float pr = 0.f;
                #pragma unroll
                for (int r = 0; r < RANK; ++r) pr = fmaf(c[r], vreg[k][r], pr);
                const float dl = hh - pr;
                e = fmaf(dl, dl, e);
                ov[k] = fmaf(fmaf(-eta, dl, hh), gam[k], bet[k]);
            }
            ep[b] = e;

            float* orow = out + (row0 + 2 * p + b) * (size_t)D;
            *reinterpret_cast<float4*>(orow + c0) = make_float4(ov[0], ov[1], ov[2], ov[3]);
            *reinterpret_cast<float4*>(orow + c1) = make_float4(ov[4], ov[5], ov[6], ov[7]);
        }

        if (p + 1 < NPH) {
            #pragma unroll
            for (int b = 0; b < 2; ++b) { hA[b][0] = hN[b][0]; hA[b][1] = hN[b][1]; }
        }
    }

    // ---- tail: e_curv for the last pair (rows 6,7 of the block)
    ep[0] = wred(ep[0]);
    ep[1] = wred(ep[1]);
    __syncthreads();                           // tot[] reads of last phase done
    if (lane == 0) { red[0][wave] = ep[0]; red[1][wave] = ep[1]; }
    __syncthreads();
    if (t == 0) {
        float4 q0 = *reinterpret_cast<const float4*>(red[0]);
        float4 q1 = *reinterpret_cast<const float4*>(red[1]);
        e_out[row0 + ROWS_PB - 2] = (q0.x + q0.y) + (q0.z + q0.w);
        e_out[row0 + ROWS_PB - 1] = (q1.x + q1.y) + (q1.z + q1.w);
    }
}

extern "C" void kernel_launch(void* const* d_in, const int* in_sizes, int n_in,
                              void* d_out, int out_size, void* d_ws, size_t ws_size,
                              hipStream_t stream) {
    const float* h     = (const float*)d_in[0];
    const float* gamma = (const float*)d_in[1];
    const float* beta  = (const float*)d_in[2];
    const float* V     = (const float*)d_in[3];
    const float* eta   = (const float*)d_in[4];
    float* out = (float*)d_out;

    const int d = in_sizes[1];                       // 2048
    const long long rows = in_sizes[0] / d;          // 16384
    float* e_out = out + (size_t)rows * d;

    dim3 grid((unsigned)(rows / ROWS_PB));
    lbonorm_kernel<<<grid, BLOCK, 0, stream>>>(h, gamma, beta, V, eta, out, e_out);
}

// Round 4
// 57.593 us; speedup vs baseline: 3.2074x; 3.2074x over previous
//
#include <hip/hip_runtime.h>
#include <hip/hip_bf16.h>

// LBONorm: fused LayerNorm + low-rank diffusion smoothing.
// rows = B*S = 16384, d = 2048 (fp32), rank = 8.
// Block = 256 thr (4 waves) owns 8 rows; thread t owns cols {4t..4t+3, 1024+4t..+3}.
// V register-resident (64 VGPR), amortized over 8 rows.
// R1: launch_bounds cap < demand -> spill (FETCH 606MB). (256,2) fixed it.
// R3: 22-value shfl butterfly -> live-temp explosion -> spill again. Reverted.
// R2 bottleneck analysis: VALUBusy 26%, BW 2.2TB/s, nothing busy -> DS-pipe
//   shuffle chains (10 vals x 6 levels of ds_swizzle, ~30-120cy each) dominate.
// R4: DPP-based wave reduce (VALU pipe, ~2cy/op, no DS) + double-buffered
//   red[] (1 barrier/row) + 12-value batch (stats + deferred e-partial).

constexpr int D       = 2048;
constexpr int RANK    = 8;
constexpr int BLOCK   = 256;
constexpr int ROWS_PB = 8;
constexpr float LN_EPS = 1e-5f;

// v_add_f32 with DPP source: x += dpp_move(x). old=0 + bound_ctrl + row_mask
// make masked/OOB lanes contribute 0.
template<int CTRL, int RM>
__device__ __forceinline__ float dppadd(float x) {
    int y = __builtin_amdgcn_update_dpp(0, __float_as_int(x), CTRL, RM, 0xf, true);
    return x + __int_as_float(y);
}
// Full 64-lane sum, result valid in lane 63 (rocPRIM gfx9 pattern).
__device__ __forceinline__ float dpp_sum64(float x) {
    x = dppadd<0x111, 0xf>(x);   // row_shr:1
    x = dppadd<0x112, 0xf>(x);   // row_shr:2
    x = dppadd<0x114, 0xf>(x);   // row_shr:4
    x = dppadd<0x118, 0xf>(x);   // row_shr:8  -> lane15 of each row = row sum
    x = dppadd<0x142, 0xa>(x);   // row_bcast:15 -> rows 1,3
    x = dppadd<0x143, 0xc>(x);   // row_bcast:31 -> rows 2,3; lane63 = total
    return x;
}

__device__ __forceinline__ void f4acc(float4& a, const float4& b) {
    a.x += b.x; a.y += b.y; a.z += b.z; a.w += b.w;
}

__global__ __launch_bounds__(BLOCK, 2)
void lbonorm_kernel(const float* __restrict__ h,
                    const float* __restrict__ gamma,
                    const float* __restrict__ beta,
                    const float* __restrict__ V,
                    const float* __restrict__ eta_p,
                    float* __restrict__ out,
                    float* __restrict__ e_out)
{
    const int t    = threadIdx.x;
    const int lane = t & 63;
    const int wave = t >> 6;

    const int c0 = t * 4;
    const int c1 = D / 2 + t * 4;

    // red[buf][wave][12]: per-wave totals {s, s2, dot0..7, e_prev, pad}
    __shared__ __align__(16) float red[2][4][12];

    const size_t row0 = (size_t)blockIdx.x * ROWS_PB;

    // ---- first row loads ASAP (overlap with V setup)
    float4 ha = *reinterpret_cast<const float4*>(h + row0 * (size_t)D + c0);
    float4 hb = *reinterpret_cast<const float4*>(h + row0 * (size_t)D + c1);

    // ---- V columns into registers: vreg[k][r] = V[r][col_k]
    float vreg[8][RANK];
    #pragma unroll
    for (int r = 0; r < RANK; ++r) {
        float4 a = *reinterpret_cast<const float4*>(V + (size_t)r * D + c0);
        float4 b = *reinterpret_cast<const float4*>(V + (size_t)r * D + c1);
        vreg[0][r] = a.x; vreg[1][r] = a.y; vreg[2][r] = a.z; vreg[3][r] = a.w;
        vreg[4][r] = b.x; vreg[5][r] = b.y; vreg[6][r] = b.z; vreg[7][r] = b.w;
    }

    const float4 g0 = *reinterpret_cast<const float4*>(gamma + c0);
    const float4 g1 = *reinterpret_cast<const float4*>(gamma + c1);
    const float4 bb0 = *reinterpret_cast<const float4*>(beta + c0);
    const float4 bb1 = *reinterpret_cast<const float4*>(beta + c1);
    const float gam[8] = {g0.x,g0.y,g0.z,g0.w,g1.x,g1.y,g1.z,g1.w};
    const float bet[8] = {bb0.x,bb0.y,bb0.z,bb0.w,bb1.x,bb1.y,bb1.z,bb1.w};
    const float eta = fminf(fmaxf(eta_p[0], 0.0f), 0.5f);

    // ---- per-rank column sums of V (uses red[1]; phase 0 uses red[0] -> no race)
    float vsum[RANK];
    {
        float vs[RANK];
        #pragma unroll
        for (int r = 0; r < RANK; ++r) {
            float v = 0.f;
            #pragma unroll
            for (int k = 0; k < 8; ++k) v += vreg[k][r];
            vs[r] = dpp_sum64(v);
        }
        if (lane == 63) {
            float4* dst = reinterpret_cast<float4*>(&red[1][wave][0]);
            dst[0] = make_float4(vs[0], vs[1], vs[2], vs[3]);
            dst[1] = make_float4(vs[4], vs[5], vs[6], vs[7]);
        }
        __syncthreads();
        float4 qa = make_float4(0.f,0.f,0.f,0.f), qb = qa;
        #pragma unroll
        for (int w = 0; w < 4; ++w) {
            f4acc(qa, reinterpret_cast<const float4*>(&red[1][w][0])[0]);
            f4acc(qb, reinterpret_cast<const float4*>(&red[1][w][0])[1]);
        }
        vsum[0]=qa.x; vsum[1]=qa.y; vsum[2]=qa.z; vsum[3]=qa.w;
        vsum[4]=qb.x; vsum[5]=qb.y; vsum[6]=qb.z; vsum[7]=qb.w;
    }

    float ep = 0.f;   // e_curv partial of the PREVIOUS row (reduced next phase)

    for (int rr = 0; rr < ROWS_PB; ++rr) {
        const size_t row = row0 + rr;

        // prefetch next row (consumed ~1 phase later)
        float4 na, nb;
        if (rr + 1 < ROWS_PB) {
            na = *reinterpret_cast<const float4*>(h + (row + 1) * (size_t)D + c0);
            nb = *reinterpret_cast<const float4*>(h + (row + 1) * (size_t)D + c1);
        }

        const float hr[8] = {ha.x,ha.y,ha.z,ha.w,hb.x,hb.y,hb.z,hb.w};

        // ---- partials: s, s2, dot[0..7], prev-row e
        float vals[11];
        {
            float s = 0.f, s2 = 0.f;
            #pragma unroll
            for (int k = 0; k < 8; ++k) { s += hr[k]; s2 = fmaf(hr[k], hr[k], s2); }
            vals[0] = s; vals[1] = s2;
            #pragma unroll
            for (int r = 0; r < RANK; ++r) {
                float dp = 0.f;
                #pragma unroll
                for (int k = 0; k < 8; ++k) dp = fmaf(hr[k], vreg[k][r], dp);
                vals[2 + r] = dp;
            }
            vals[10] = ep;
        }
        #pragma unroll
        for (int n = 0; n < 11; ++n) vals[n] = dpp_sum64(vals[n]);

        const int buf = rr & 1;
        if (lane == 63) {
            float4* dst = reinterpret_cast<float4*>(&red[buf][wave][0]);
            dst[0] = make_float4(vals[0], vals[1], vals[2], vals[3]);
            dst[1] = make_float4(vals[4], vals[5], vals[6], vals[7]);
            dst[2] = make_float4(vals[8], vals[9], vals[10], 0.f);
        }
        __syncthreads();

        float4 q0 = make_float4(0.f,0.f,0.f,0.f), q1 = q0, q2 = q0;
        #pragma unroll
        for (int w = 0; w < 4; ++w) {
            const float4* src = reinterpret_cast<const float4*>(&red[buf][w][0]);
            f4acc(q0, src[0]); f4acc(q1, src[1]); f4acc(q2, src[2]);
        }

        if (t == 0 && rr > 0) e_out[row - 1] = q2.z;   // previous row's e_curv

        const float mu  = q0.x * (1.0f / D);
        const float var = fmaxf(q0.y * (1.0f / D) - mu * mu, 0.0f);
        const float inv = rsqrtf(var + LN_EPS);
        const float dot[8] = {q0.z, q0.w, q1.x, q1.y, q1.z, q1.w, q2.x, q2.y};
        float c[RANK];
        #pragma unroll
        for (int r = 0; r < RANK; ++r)
            c[r] = inv * (dot[r] - mu * vsum[r]);

        // ---- epilogue
        float e = 0.f, ov[8];
        #pragma unroll
        for (int k = 0; k < 8; ++k) {
            const float hh = (hr[k] - mu) * inv;
            float pr = 0.f;
            #pragma unroll
            for (int r = 0; r < RANK; ++r) pr = fmaf(c[r], vreg[k][r], pr);
            const float dl = hh - pr;
            e = fmaf(dl, dl, e);
            ov[k] = fmaf(fmaf(-eta, dl, hh), gam[k], bet[k]);
        }
        ep = e;

        float* orow = out + row * (size_t)D;
        *reinterpret_cast<float4*>(orow + c0) = make_float4(ov[0], ov[1], ov[2], ov[3]);
        *reinterpret_cast<float4*>(orow + c1) = make_float4(ov[4], ov[5], ov[6], ov[7]);

        ha = na; hb = nb;
    }

    // ---- tail: e_curv of the last row (red[0] free: phase-7 used red[1],
    // phase-6 readers finished before barrier 7)
    ep = dpp_sum64(ep);
    if (lane == 63) red[0][wave][0] = ep;
    __syncthreads();
    if (t == 0)
        e_out[row0 + ROWS_PB - 1] = red[0][0][0] + red[0][1][0] + red[0][2][0] + red[0][3][0];
}

extern "C" void kernel_launch(void* const* d_in, const int* in_sizes, int n_in,
                              void* d_out, int out_size, void* d_ws, size_t ws_size,
                              hipStream_t stream) {
    const float* h     = (const float*)d_in[0];
    const float* gamma = (const float*)d_in[1];
    const float* beta  = (const float*)d_in[2];
    const float* V     = (const float*)d_in[3];
    const float* eta   = (const float*)d_in[4];
    float* out = (float*)d_out;

    const int d = in_sizes[1];                       // 2048
    const long long rows = in_sizes[0] / d;          // 16384
    float* e_out = out + (size_t)rows * d;

    dim3 grid((unsigned)(rows / ROWS_PB));
    lbonorm_kernel<<<grid, BLOCK, 0, stream>>>(h, gamma, beta, V, eta, out, e_out);
}

// Round 5
// 56.636 us; speedup vs baseline: 3.2617x; 1.0169x over previous
//
#include <hip/hip_runtime.h>
#include <hip/hip_bf16.h>

// LBONorm: fused LayerNorm + low-rank diffusion smoothing.
// rows = B*S = 16384, d = 2048 (fp32), rank = 8.
// Block = 256 thr (4 waves) owns 8 rows; thread t owns cols {4t..4t+3, 1024+4t..+3}.
// V register-resident, amortized over 8 rows.
// R1: launch_bounds cap < demand -> spill. (256,2) fixed.
// R3: 22-value batch -> live-temp explosion -> spill. Reverted.
// R4: DPP wave-reduce replaced shfl butterfly: 81.5 -> 57.6 us (VALUBusy 26->43%).
// R5: (a) cross-wave combine: 12 broadcast ds_read_b128 -> 3 reads + quad_perm
//     DPP adds (LDS pipe -> VALU); (b) packed fp32 (v_pk_fma_f32) via float2
//     ext-vectors; (c) prefetch depth 2.

constexpr int D       = 2048;
constexpr int RANK    = 8;
constexpr int BLOCK   = 256;
constexpr int ROWS_PB = 8;
constexpr float LN_EPS = 1e-5f;

using f2 = __attribute__((ext_vector_type(2))) float;

__device__ __forceinline__ f2 f2fma(f2 a, f2 b, f2 c) {
    return __builtin_elementwise_fma(a, b, c);
}

// x += dpp_move(x); old=0 + bound_ctrl => masked/OOB lanes contribute 0.
template<int CTRL, int RM>
__device__ __forceinline__ float dppadd(float x) {
    int y = __builtin_amdgcn_update_dpp(0, __float_as_int(x), CTRL, RM, 0xf, true);
    return x + __int_as_float(y);
}
// Full 64-lane sum, result valid in lane 63.
__device__ __forceinline__ float dpp_sum64(float x) {
    x = dppadd<0x111, 0xf>(x);   // row_shr:1
    x = dppadd<0x112, 0xf>(x);   // row_shr:2
    x = dppadd<0x114, 0xf>(x);   // row_shr:4
    x = dppadd<0x118, 0xf>(x);   // row_shr:8
    x = dppadd<0x142, 0xa>(x);   // row_bcast:15
    x = dppadd<0x143, 0xc>(x);   // row_bcast:31 -> lane63 = total
    return x;
}
// quad_perm add: sums groups of 4 consecutive lanes (all lanes get total).
template<int PAT>
__device__ __forceinline__ float qpadd(float x) {
    int y = __builtin_amdgcn_update_dpp(0, __float_as_int(x), PAT, 0xf, 0xf, true);
    return x + __int_as_float(y);
}
__device__ __forceinline__ void quad_reduce(float4& q) {
    q.x = qpadd<0xB1>(q.x); q.y = qpadd<0xB1>(q.y);
    q.z = qpadd<0xB1>(q.z); q.w = qpadd<0xB1>(q.w);   // xor 1: [1,0,3,2]
    q.x = qpadd<0x4E>(q.x); q.y = qpadd<0x4E>(q.y);
    q.z = qpadd<0x4E>(q.z); q.w = qpadd<0x4E>(q.w);   // xor 2: [2,3,0,1]
}

__global__ __launch_bounds__(BLOCK, 2)
void lbonorm_kernel(const float* __restrict__ h,
                    const float* __restrict__ gamma,
                    const float* __restrict__ beta,
                    const float* __restrict__ V,
                    const float* __restrict__ eta_p,
                    float* __restrict__ out,
                    float* __restrict__ e_out)
{
    const int t    = threadIdx.x;
    const int lane = t & 63;
    const int wave = t >> 6;

    const int c0 = t * 4;
    const int c1 = D / 2 + t * 4;

    // red[buf][wave][12]: per-wave totals {s, s2, dot0..7, e_prev, pad}
    __shared__ __align__(16) float red[2][4][12];

    const size_t row0 = (size_t)blockIdx.x * ROWS_PB;

    // ---- first rows' loads ASAP (overlap with V setup)
    float4 ha = *reinterpret_cast<const float4*>(h + row0 * (size_t)D + c0);
    float4 hb = *reinterpret_cast<const float4*>(h + row0 * (size_t)D + c1);
    float4 na = *reinterpret_cast<const float4*>(h + (row0 + 1) * (size_t)D + c0);
    float4 nb = *reinterpret_cast<const float4*>(h + (row0 + 1) * (size_t)D + c1);

    // ---- V column pairs into registers: vreg[k][r] = {V[r][..2k], V[r][..2k+1]}
    f2 vreg[4][RANK];
    #pragma unroll
    for (int r = 0; r < RANK; ++r) {
        float4 a = *reinterpret_cast<const float4*>(V + (size_t)r * D + c0);
        float4 b = *reinterpret_cast<const float4*>(V + (size_t)r * D + c1);
        vreg[0][r] = f2{a.x, a.y}; vreg[1][r] = f2{a.z, a.w};
        vreg[2][r] = f2{b.x, b.y}; vreg[3][r] = f2{b.z, b.w};
    }

    const float4 g0 = *reinterpret_cast<const float4*>(gamma + c0);
    const float4 g1 = *reinterpret_cast<const float4*>(gamma + c1);
    const float4 bb0 = *reinterpret_cast<const float4*>(beta + c0);
    const float4 bb1 = *reinterpret_cast<const float4*>(beta + c1);
    const f2 gam[4] = {f2{g0.x,g0.y}, f2{g0.z,g0.w}, f2{g1.x,g1.y}, f2{g1.z,g1.w}};
    const f2 bet[4] = {f2{bb0.x,bb0.y}, f2{bb0.z,bb0.w}, f2{bb1.x,bb1.y}, f2{bb1.z,bb1.w}};
    const float eta = fminf(fmaxf(eta_p[0], 0.0f), 0.5f);

    // ---- per-rank column sums of V (uses red[1]; phase 0 uses red[0])
    float vsum[RANK];
    {
        float vs[RANK];
        #pragma unroll
        for (int r = 0; r < RANK; ++r) {
            f2 v = vreg[0][r] + vreg[1][r] + vreg[2][r] + vreg[3][r];
            vs[r] = dpp_sum64(v.x + v.y);
        }
        if (lane == 63) {
            float4* dst = reinterpret_cast<float4*>(&red[1][wave][0]);
            dst[0] = make_float4(vs[0], vs[1], vs[2], vs[3]);
            dst[1] = make_float4(vs[4], vs[5], vs[6], vs[7]);
        }
        __syncthreads();
        const float4* src = reinterpret_cast<const float4*>(&red[1][lane & 3][0]);
        float4 qa = src[0], qb = src[1];
        quad_reduce(qa); quad_reduce(qb);
        vsum[0]=qa.x; vsum[1]=qa.y; vsum[2]=qa.z; vsum[3]=qa.w;
        vsum[4]=qb.x; vsum[5]=qb.y; vsum[6]=qb.z; vsum[7]=qb.w;
    }

    float ep = 0.f;   // e_curv partial of the PREVIOUS row

    for (int rr = 0; rr < ROWS_PB; ++rr) {
        const size_t row = row0 + rr;

        // prefetch row+2 (depth 2)
        float4 pa, pb;
        if (rr + 2 < ROWS_PB) {
            pa = *reinterpret_cast<const float4*>(h + (row + 2) * (size_t)D + c0);
            pb = *reinterpret_cast<const float4*>(h + (row + 2) * (size_t)D + c1);
        }

        const f2 h2[4] = {f2{ha.x,ha.y}, f2{ha.z,ha.w}, f2{hb.x,hb.y}, f2{hb.z,hb.w}};

        // ---- partials: s, s2, dot[0..7] (packed fp32), prev-row e
        float vals[11];
        {
            f2 s  = (h2[0] + h2[1]) + (h2[2] + h2[3]);
            f2 s2 = f2fma(h2[0], h2[0], f2fma(h2[1], h2[1],
                    f2fma(h2[2], h2[2], h2[3] * h2[3])));
            vals[0] = s.x + s.y;
            vals[1] = s2.x + s2.y;
            #pragma unroll
            for (int r = 0; r < RANK; ++r) {
                f2 d = f2fma(h2[0], vreg[0][r], f2fma(h2[1], vreg[1][r],
                       f2fma(h2[2], vreg[2][r], h2[3] * vreg[3][r])));
                vals[2 + r] = d.x + d.y;
            }
            vals[10] = ep;
        }
        #pragma unroll
        for (int n = 0; n < 11; ++n) vals[n] = dpp_sum64(vals[n]);

        const int buf = rr & 1;
        if (lane == 63) {
            float4* dst = reinterpret_cast<float4*>(&red[buf][wave][0]);
            dst[0] = make_float4(vals[0], vals[1], vals[2], vals[3]);
            dst[1] = make_float4(vals[4], vals[5], vals[6], vals[7]);
            dst[2] = make_float4(vals[8], vals[9], vals[10], 0.f);
        }
        __syncthreads();

        // ---- cross-wave combine: 3 reads of wave (lane&3)'s slot + quad_perm
        const float4* src = reinterpret_cast<const float4*>(&red[buf][lane & 3][0]);
        float4 q0 = src[0], q1 = src[1], q2 = src[2];
        quad_reduce(q0); quad_reduce(q1); quad_reduce(q2);

        if (t == 0 && rr > 0) e_out[row - 1] = q2.z;   // previous row's e_curv

        const float mu  = q0.x * (1.0f / D);
        const float var = fmaxf(q0.y * (1.0f / D) - mu * mu, 0.0f);
        const float inv = rsqrtf(var + LN_EPS);
        const float dot[8] = {q0.z, q0.w, q1.x, q1.y, q1.z, q1.w, q2.x, q2.y};
        f2 c2[RANK];
        #pragma unroll
        for (int r = 0; r < RANK; ++r) {
            const float c = inv * (dot[r] - mu * vsum[r]);
            c2[r] = f2{c, c};
        }

        // ---- epilogue (packed)
        const f2 inv2  = f2{inv, inv};
        const f2 nmi2  = f2{-mu * inv, -mu * inv};
        const f2 neta2 = f2{-eta, -eta};
        f2 e2 = f2{0.f, 0.f};
        f2 ov[4];
        #pragma unroll
        for (int k = 0; k < 4; ++k) {
            const f2 hh = f2fma(h2[k], inv2, nmi2);
            f2 pr = c2[0] * vreg[0 == k ? 0 : 0][0];   // placeholder replaced below
            pr = c2[0] * vreg[k][0];
            #pragma unroll
            for (int r = 1; r < RANK; ++r) pr = f2fma(c2[r], vreg[k][r], pr);
            const f2 dl = hh - pr;
            e2 = f2fma(dl, dl, e2);
            const f2 sm = f2fma(neta2, dl, hh);
            ov[k] = f2fma(sm, gam[k], bet[k]);
        }
        ep = e2.x + e2.y;

        float* orow = out + row * (size_t)D;
        *reinterpret_cast<float4*>(orow + c0) = make_float4(ov[0].x, ov[0].y, ov[1].x, ov[1].y);
        *reinterpret_cast<float4*>(orow + c1) = make_float4(ov[2].x, ov[2].y, ov[3].x, ov[3].y);

        ha = na; hb = nb;
        if (rr + 2 < ROWS_PB) { na = pa; nb = pb; }
    }

    // ---- tail: e_curv of the last row
    ep = dpp_sum64(ep);
    if (lane == 63) red[0][wave][0] = ep;
    __syncthreads();
    if (t == 0)
        e_out[row0 + ROWS_PB - 1] = red[0][0][0] + red[0][1][0] + red[0][2][0] + red[0][3][0];
}

extern "C" void kernel_launch(void* const* d_in, const int* in_sizes, int n_in,
                              void* d_out, int out_size, void* d_ws, size_t ws_size,
                              hipStream_t stream) {
    const float* h     = (const float*)d_in[0];
    const float* gamma = (const float*)d_in[1];
    const float* beta  = (const float*)d_in[2];
    const float* V     = (const float*)d_in[3];
    const float* eta   = (const float*)d_in[4];
    float* out = (float*)d_out;

    const int d = in_sizes[1];                       // 2048
    const long long rows = in_sizes[0] / d;          // 16384
    float* e_out = out + (size_t)rows * d;

    dim3 grid((unsigned)(rows / ROWS_PB));
    lbonorm_kernel<<<grid, BLOCK, 0, stream>>>(h, gamma, beta, V, eta, out, e_out);
}

// Round 6
// 56.456 us; speedup vs baseline: 3.2721x; 1.0032x over previous
//
#include <hip/hip_runtime.h>
#include <hip/hip_bf16.h>

// LBONorm: fused LayerNorm + low-rank diffusion smoothing.
// rows = B*S = 16384, d = 2048 (fp32), rank = 8.
// Block = 256 thr (4 waves) owns 8 rows; thread t owns cols {4t..4t+3, 1024+4t..+3}.
// R1: launch_bounds cap < demand -> spill. (256,2) fixed.
// R3: 22-value batch -> live-temp explosion -> spill. Reverted.
// R4: DPP wave-reduce replaced shfl butterfly: 81.5 -> 57.6 us.
// R5: quad_perm combine + packed fp32: neutral (56.6 us) -> NOT VALU-bound.
// R6 theory: __syncthreads makes hipcc emit s_waitcnt vmcnt(0) before s_barrier,
//   draining the row+2 prefetch EVERY phase (~900cy HBM latency on the critical
//   path per row). Fix: raw barrier with counted wait (HK technique):
//   "s_waitcnt lgkmcnt(0); s_barrier" -- LDS write drained (cross-wave red[]
//   visibility), global loads/stores stay in flight across the barrier.

constexpr int D       = 2048;
constexpr int RANK    = 8;
constexpr int BLOCK   = 256;
constexpr int ROWS_PB = 8;
constexpr float LN_EPS = 1e-5f;

using f2 = __attribute__((ext_vector_type(2))) float;

__device__ __forceinline__ f2 f2fma(f2 a, f2 b, f2 c) {
    return __builtin_elementwise_fma(a, b, c);
}

// Barrier that drains ONLY lgkmcnt (LDS) -- global loads/stores stay in flight.
// __syncthreads() would emit s_waitcnt vmcnt(0) and kill the prefetch.
__device__ __forceinline__ void barrier_lds() {
    asm volatile("s_waitcnt lgkmcnt(0)\n\ts_barrier" ::: "memory");
}

// x += dpp_move(x); old=0 + bound_ctrl => masked/OOB lanes contribute 0.
template<int CTRL, int RM>
__device__ __forceinline__ float dppadd(float x) {
    int y = __builtin_amdgcn_update_dpp(0, __float_as_int(x), CTRL, RM, 0xf, true);
    return x + __int_as_float(y);
}
// Full 64-lane sum, result valid in lane 63.
__device__ __forceinline__ float dpp_sum64(float x) {
    x = dppadd<0x111, 0xf>(x);   // row_shr:1
    x = dppadd<0x112, 0xf>(x);   // row_shr:2
    x = dppadd<0x114, 0xf>(x);   // row_shr:4
    x = dppadd<0x118, 0xf>(x);   // row_shr:8
    x = dppadd<0x142, 0xa>(x);   // row_bcast:15
    x = dppadd<0x143, 0xc>(x);   // row_bcast:31 -> lane63 = total
    return x;
}
// quad_perm add: sums groups of 4 consecutive lanes (all lanes get total).
template<int PAT>
__device__ __forceinline__ float qpadd(float x) {
    int y = __builtin_amdgcn_update_dpp(0, __float_as_int(x), PAT, 0xf, 0xf, true);
    return x + __int_as_float(y);
}
__device__ __forceinline__ void quad_reduce(float4& q) {
    q.x = qpadd<0xB1>(q.x); q.y = qpadd<0xB1>(q.y);
    q.z = qpadd<0xB1>(q.z); q.w = qpadd<0xB1>(q.w);   // xor 1: [1,0,3,2]
    q.x = qpadd<0x4E>(q.x); q.y = qpadd<0x4E>(q.y);
    q.z = qpadd<0x4E>(q.z); q.w = qpadd<0x4E>(q.w);   // xor 2: [2,3,0,1]
}

__global__ __launch_bounds__(BLOCK, 2)
void lbonorm_kernel(const float* __restrict__ h,
                    const float* __restrict__ gamma,
                    const float* __restrict__ beta,
                    const float* __restrict__ V,
                    const float* __restrict__ eta_p,
                    float* __restrict__ out,
                    float* __restrict__ e_out)
{
    const int t    = threadIdx.x;
    const int lane = t & 63;
    const int wave = t >> 6;

    const int c0 = t * 4;
    const int c1 = D / 2 + t * 4;

    // red[buf][wave][12]: per-wave totals {s, s2, dot0..7, e_prev, pad}
    __shared__ __align__(16) float red[2][4][12];

    const size_t row0 = (size_t)blockIdx.x * ROWS_PB;

    // ---- first rows' loads ASAP (overlap with V setup)
    float4 ha = *reinterpret_cast<const float4*>(h + row0 * (size_t)D + c0);
    float4 hb = *reinterpret_cast<const float4*>(h + row0 * (size_t)D + c1);
    float4 na = *reinterpret_cast<const float4*>(h + (row0 + 1) * (size_t)D + c0);
    float4 nb = *reinterpret_cast<const float4*>(h + (row0 + 1) * (size_t)D + c1);

    // ---- V column pairs into registers: vreg[k][r] = {V[r][..2k], V[r][..2k+1]}
    f2 vreg[4][RANK];
    #pragma unroll
    for (int r = 0; r < RANK; ++r) {
        float4 a = *reinterpret_cast<const float4*>(V + (size_t)r * D + c0);
        float4 b = *reinterpret_cast<const float4*>(V + (size_t)r * D + c1);
        vreg[0][r] = f2{a.x, a.y}; vreg[1][r] = f2{a.z, a.w};
        vreg[2][r] = f2{b.x, b.y}; vreg[3][r] = f2{b.z, b.w};
    }

    const float4 g0 = *reinterpret_cast<const float4*>(gamma + c0);
    const float4 g1 = *reinterpret_cast<const float4*>(gamma + c1);
    const float4 bb0 = *reinterpret_cast<const float4*>(beta + c0);
    const float4 bb1 = *reinterpret_cast<const float4*>(beta + c1);
    const f2 gam[4] = {f2{g0.x,g0.y}, f2{g0.z,g0.w}, f2{g1.x,g1.y}, f2{g1.z,g1.w}};
    const f2 bet[4] = {f2{bb0.x,bb0.y}, f2{bb0.z,bb0.w}, f2{bb1.x,bb1.y}, f2{bb1.z,bb1.w}};
    const float eta = fminf(fmaxf(eta_p[0], 0.0f), 0.5f);

    // ---- per-rank column sums of V (uses red[1]; phase 0 uses red[0])
    float vsum[RANK];
    {
        float vs[RANK];
        #pragma unroll
        for (int r = 0; r < RANK; ++r) {
            f2 v = vreg[0][r] + vreg[1][r] + vreg[2][r] + vreg[3][r];
            vs[r] = dpp_sum64(v.x + v.y);
        }
        if (lane == 63) {
            float4* dst = reinterpret_cast<float4*>(&red[1][wave][0]);
            dst[0] = make_float4(vs[0], vs[1], vs[2], vs[3]);
            dst[1] = make_float4(vs[4], vs[5], vs[6], vs[7]);
        }
        barrier_lds();
        const float4* src = reinterpret_cast<const float4*>(&red[1][lane & 3][0]);
        float4 qa = src[0], qb = src[1];
        quad_reduce(qa); quad_reduce(qb);
        vsum[0]=qa.x; vsum[1]=qa.y; vsum[2]=qa.z; vsum[3]=qa.w;
        vsum[4]=qb.x; vsum[5]=qb.y; vsum[6]=qb.z; vsum[7]=qb.w;
    }

    float ep = 0.f;   // e_curv partial of the PREVIOUS row

    for (int rr = 0; rr < ROWS_PB; ++rr) {
        const size_t row = row0 + rr;

        // prefetch row+2 (depth 2) -- survives the barrier now
        float4 pa, pb;
        if (rr + 2 < ROWS_PB) {
            pa = *reinterpret_cast<const float4*>(h + (row + 2) * (size_t)D + c0);
            pb = *reinterpret_cast<const float4*>(h + (row + 2) * (size_t)D + c1);
        }

        const f2 h2[4] = {f2{ha.x,ha.y}, f2{ha.z,ha.w}, f2{hb.x,hb.y}, f2{hb.z,hb.w}};

        // ---- partials: s, s2, dot[0..7] (packed fp32), prev-row e
        float vals[11];
        {
            f2 s  = (h2[0] + h2[1]) + (h2[2] + h2[3]);
            f2 s2 = f2fma(h2[0], h2[0], f2fma(h2[1], h2[1],
                    f2fma(h2[2], h2[2], h2[3] * h2[3])));
            vals[0] = s.x + s.y;
            vals[1] = s2.x + s2.y;
            #pragma unroll
            for (int r = 0; r < RANK; ++r) {
                f2 d = f2fma(h2[0], vreg[0][r], f2fma(h2[1], vreg[1][r],
                       f2fma(h2[2], vreg[2][r], h2[3] * vreg[3][r])));
                vals[2 + r] = d.x + d.y;
            }
            vals[10] = ep;
        }
        #pragma unroll
        for (int n = 0; n < 11; ++n) vals[n] = dpp_sum64(vals[n]);

        const int buf = rr & 1;
        if (lane == 63) {
            float4* dst = reinterpret_cast<float4*>(&red[buf][wave][0]);
            dst[0] = make_float4(vals[0], vals[1], vals[2], vals[3]);
            dst[1] = make_float4(vals[4], vals[5], vals[6], vals[7]);
            dst[2] = make_float4(vals[8], vals[9], vals[10], 0.f);
        }
        barrier_lds();

        // ---- cross-wave combine: 3 reads of wave (lane&3)'s slot + quad_perm
        const float4* src = reinterpret_cast<const float4*>(&red[buf][lane & 3][0]);
        float4 q0 = src[0], q1 = src[1], q2 = src[2];
        quad_reduce(q0); quad_reduce(q1); quad_reduce(q2);

        if (t == 0 && rr > 0) e_out[row - 1] = q2.z;   // previous row's e_curv

        const float mu  = q0.x * (1.0f / D);
        const float var = fmaxf(q0.y * (1.0f / D) - mu * mu, 0.0f);
        const float inv = rsqrtf(var + LN_EPS);
        const float dot[8] = {q0.z, q0.w, q1.x, q1.y, q1.z, q1.w, q2.x, q2.y};
        f2 c2[RANK];
        #pragma unroll
        for (int r = 0; r < RANK; ++r) {
            const float c = inv * (dot[r] - mu * vsum[r]);
            c2[r] = f2{c, c};
        }

        // ---- epilogue (packed)
        const f2 inv2  = f2{inv, inv};
        const f2 nmi2  = f2{-mu * inv, -mu * inv};
        const f2 neta2 = f2{-eta, -eta};
        f2 e2 = f2{0.f, 0.f};
        f2 ov[4];
        #pragma unroll
        for (int k = 0; k < 4; ++k) {
            const f2 hh = f2fma(h2[k], inv2, nmi2);
            f2 pr = c2[0] * vreg[k][0];
            #pragma unroll
            for (int r = 1; r < RANK; ++r) pr = f2fma(c2[r], vreg[k][r], pr);
            const f2 dl = hh - pr;
            e2 = f2fma(dl, dl, e2);
            const f2 sm = f2fma(neta2, dl, hh);
            ov[k] = f2fma(sm, gam[k], bet[k]);
        }
        ep = e2.x + e2.y;

        float* orow = out + row * (size_t)D;
        *reinterpret_cast<float4*>(orow + c0) = make_float4(ov[0].x, ov[0].y, ov[1].x, ov[1].y);
        *reinterpret_cast<float4*>(orow + c1) = make_float4(ov[2].x, ov[2].y, ov[3].x, ov[3].y);

        ha = na; hb = nb;
        if (rr + 2 < ROWS_PB) { na = pa; nb = pb; }
    }

    // ---- tail: e_curv of the last row
    ep = dpp_sum64(ep);
    if (lane == 63) red[0][wave][0] = ep;
    barrier_lds();
    if (t == 0)
        e_out[row0 + ROWS_PB - 1] = red[0][0][0] + red[0][1][0] + red[0][2][0] + red[0][3][0];
}

extern "C" void kernel_launch(void* const* d_in, const int* in_sizes, int n_in,
                              void* d_out, int out_size, void* d_ws, size_t ws_size,
                              hipStream_t stream) {
    const float* h     = (const float*)d_in[0];
    const float* gamma = (const float*)d_in[1];
    const float* beta  = (const float*)d_in[2];
    const float* V     = (const float*)d_in[3];
    const float* eta   = (const float*)d_in[4];
    float* out = (float*)d_out;

    const int d = in_sizes[1];                       // 2048
    const long long rows = in_sizes[0] / d;          // 16384
    float* e_out = out + (size_t)rows * d;

    dim3 grid((unsigned)(rows / ROWS_PB));
    lbonorm_kernel<<<grid, BLOCK, 0, stream>>>(h, gamma, beta, V, eta, out, e_out);
}

// Round 7
// 55.179 us; speedup vs baseline: 3.3478x; 1.0231x over previous
//
#include <hip/hip_runtime.h>
#include <hip/hip_bf16.h>

// LBONorm: fused LayerNorm + low-rank diffusion smoothing.
// rows = B*S = 16384, d = 2048 (fp32), rank = 8.
// Block = 256 thr (4 waves) owns 8 rows; thread t owns cols {4t..4t+3, 1024+4t..+3}.
// R1: launch_bounds cap < demand -> spill. (256,2) fixed.
// R3: 22-value batch -> live-temp explosion -> spill. Reverted.
// R4: DPP wave-reduce replaced shfl butterfly: 81.5 -> 57.6 us.
// R5: quad_perm combine + packed fp32: neutral -> NOT VALU-issue-bound.
// R6: counted-wait barrier (lgkmcnt only): neutral -> not barrier-drain-bound.
// R7 theory: h(128MB)+out(128MB) = 256MB = exactly L3 size -> out's write
//   allocations evict half of h every replay (FETCH=66MB = h/2). Fix: NT
//   stores for out/e_out (no L3 allocate) -> h stays L3-resident across graph
//   replays, HBM carries only the write stream.

constexpr int D       = 2048;
constexpr int RANK    = 8;
constexpr int BLOCK   = 256;
constexpr int ROWS_PB = 8;
constexpr float LN_EPS = 1e-5f;

using f2  = __attribute__((ext_vector_type(2))) float;
using f4v = __attribute__((ext_vector_type(4))) float;

__device__ __forceinline__ f2 f2fma(f2 a, f2 b, f2 c) {
    return __builtin_elementwise_fma(a, b, c);
}

// NT store: no L2/L3 allocate -- keeps h resident in Infinity Cache.
__device__ __forceinline__ void nt_store4(float* p, float x, float y, float z, float w) {
    f4v v = {x, y, z, w};
    __builtin_nontemporal_store(v, reinterpret_cast<f4v*>(p));
}

// Barrier that drains ONLY lgkmcnt (LDS) -- global loads/stores stay in flight.
__device__ __forceinline__ void barrier_lds() {
    asm volatile("s_waitcnt lgkmcnt(0)\n\ts_barrier" ::: "memory");
}

// x += dpp_move(x); old=0 + bound_ctrl => masked/OOB lanes contribute 0.
template<int CTRL, int RM>
__device__ __forceinline__ float dppadd(float x) {
    int y = __builtin_amdgcn_update_dpp(0, __float_as_int(x), CTRL, RM, 0xf, true);
    return x + __int_as_float(y);
}
// Full 64-lane sum, result valid in lane 63.
__device__ __forceinline__ float dpp_sum64(float x) {
    x = dppadd<0x111, 0xf>(x);   // row_shr:1
    x = dppadd<0x112, 0xf>(x);   // row_shr:2
    x = dppadd<0x114, 0xf>(x);   // row_shr:4
    x = dppadd<0x118, 0xf>(x);   // row_shr:8
    x = dppadd<0x142, 0xa>(x);   // row_bcast:15
    x = dppadd<0x143, 0xc>(x);   // row_bcast:31 -> lane63 = total
    return x;
}
// quad_perm add: sums groups of 4 consecutive lanes (all lanes get total).
template<int PAT>
__device__ __forceinline__ float qpadd(float x) {
    int y = __builtin_amdgcn_update_dpp(0, __float_as_int(x), PAT, 0xf, 0xf, true);
    return x + __int_as_float(y);
}
__device__ __forceinline__ void quad_reduce(float4& q) {
    q.x = qpadd<0xB1>(q.x); q.y = qpadd<0xB1>(q.y);
    q.z = qpadd<0xB1>(q.z); q.w = qpadd<0xB1>(q.w);   // xor 1: [1,0,3,2]
    q.x = qpadd<0x4E>(q.x); q.y = qpadd<0x4E>(q.y);
    q.z = qpadd<0x4E>(q.z); q.w = qpadd<0x4E>(q.w);   // xor 2: [2,3,0,1]
}

__global__ __launch_bounds__(BLOCK, 2)
void lbonorm_kernel(const float* __restrict__ h,
                    const float* __restrict__ gamma,
                    const float* __restrict__ beta,
                    const float* __restrict__ V,
                    const float* __restrict__ eta_p,
                    float* __restrict__ out,
                    float* __restrict__ e_out)
{
    const int t    = threadIdx.x;
    const int lane = t & 63;
    const int wave = t >> 6;

    const int c0 = t * 4;
    const int c1 = D / 2 + t * 4;

    // red[buf][wave][12]: per-wave totals {s, s2, dot0..7, e_prev, pad}
    __shared__ __align__(16) float red[2][4][12];

    const size_t row0 = (size_t)blockIdx.x * ROWS_PB;

    // ---- first rows' loads ASAP (overlap with V setup)
    float4 ha = *reinterpret_cast<const float4*>(h + row0 * (size_t)D + c0);
    float4 hb = *reinterpret_cast<const float4*>(h + row0 * (size_t)D + c1);
    float4 na = *reinterpret_cast<const float4*>(h + (row0 + 1) * (size_t)D + c0);
    float4 nb = *reinterpret_cast<const float4*>(h + (row0 + 1) * (size_t)D + c1);

    // ---- V column pairs into registers: vreg[k][r] = {V[r][..2k], V[r][..2k+1]}
    f2 vreg[4][RANK];
    #pragma unroll
    for (int r = 0; r < RANK; ++r) {
        float4 a = *reinterpret_cast<const float4*>(V + (size_t)r * D + c0);
        float4 b = *reinterpret_cast<const float4*>(V + (size_t)r * D + c1);
        vreg[0][r] = f2{a.x, a.y}; vreg[1][r] = f2{a.z, a.w};
        vreg[2][r] = f2{b.x, b.y}; vreg[3][r] = f2{b.z, b.w};
    }

    const float4 g0 = *reinterpret_cast<const float4*>(gamma + c0);
    const float4 g1 = *reinterpret_cast<const float4*>(gamma + c1);
    const float4 bb0 = *reinterpret_cast<const float4*>(beta + c0);
    const float4 bb1 = *reinterpret_cast<const float4*>(beta + c1);
    const f2 gam[4] = {f2{g0.x,g0.y}, f2{g0.z,g0.w}, f2{g1.x,g1.y}, f2{g1.z,g1.w}};
    const f2 bet[4] = {f2{bb0.x,bb0.y}, f2{bb0.z,bb0.w}, f2{bb1.x,bb1.y}, f2{bb1.z,bb1.w}};
    const float eta = fminf(fmaxf(eta_p[0], 0.0f), 0.5f);

    // ---- per-rank column sums of V (uses red[1]; phase 0 uses red[0])
    float vsum[RANK];
    {
        float vs[RANK];
        #pragma unroll
        for (int r = 0; r < RANK; ++r) {
            f2 v = vreg[0][r] + vreg[1][r] + vreg[2][r] + vreg[3][r];
            vs[r] = dpp_sum64(v.x + v.y);
        }
        if (lane == 63) {
            float4* dst = reinterpret_cast<float4*>(&red[1][wave][0]);
            dst[0] = make_float4(vs[0], vs[1], vs[2], vs[3]);
            dst[1] = make_float4(vs[4], vs[5], vs[6], vs[7]);
        }
        barrier_lds();
        const float4* src = reinterpret_cast<const float4*>(&red[1][lane & 3][0]);
        float4 qa = src[0], qb = src[1];
        quad_reduce(qa); quad_reduce(qb);
        vsum[0]=qa.x; vsum[1]=qa.y; vsum[2]=qa.z; vsum[3]=qa.w;
        vsum[4]=qb.x; vsum[5]=qb.y; vsum[6]=qb.z; vsum[7]=qb.w;
    }

    float ep = 0.f;   // e_curv partial of the PREVIOUS row

    for (int rr = 0; rr < ROWS_PB; ++rr) {
        const size_t row = row0 + rr;

        // prefetch row+2 (depth 2) -- survives the barrier (counted wait)
        float4 pa, pb;
        if (rr + 2 < ROWS_PB) {
            pa = *reinterpret_cast<const float4*>(h + (row + 2) * (size_t)D + c0);
            pb = *reinterpret_cast<const float4*>(h + (row + 2) * (size_t)D + c1);
        }

        const f2 h2[4] = {f2{ha.x,ha.y}, f2{ha.z,ha.w}, f2{hb.x,hb.y}, f2{hb.z,hb.w}};

        // ---- partials: s, s2, dot[0..7] (packed fp32), prev-row e
        float vals[11];
        {
            f2 s  = (h2[0] + h2[1]) + (h2[2] + h2[3]);
            f2 s2 = f2fma(h2[0], h2[0], f2fma(h2[1], h2[1],
                    f2fma(h2[2], h2[2], h2[3] * h2[3])));
            vals[0] = s.x + s.y;
            vals[1] = s2.x + s2.y;
            #pragma unroll
            for (int r = 0; r < RANK; ++r) {
                f2 d = f2fma(h2[0], vreg[0][r], f2fma(h2[1], vreg[1][r],
                       f2fma(h2[2], vreg[2][r], h2[3] * vreg[3][r])));
                vals[2 + r] = d.x + d.y;
            }
            vals[10] = ep;
        }
        #pragma unroll
        for (int n = 0; n < 11; ++n) vals[n] = dpp_sum64(vals[n]);

        const int buf = rr & 1;
        if (lane == 63) {
            float4* dst = reinterpret_cast<float4*>(&red[buf][wave][0]);
            dst[0] = make_float4(vals[0], vals[1], vals[2], vals[3]);
            dst[1] = make_float4(vals[4], vals[5], vals[6], vals[7]);
            dst[2] = make_float4(vals[8], vals[9], vals[10], 0.f);
        }
        barrier_lds();

        // ---- cross-wave combine: 3 reads of wave (lane&3)'s slot + quad_perm
        const float4* src = reinterpret_cast<const float4*>(&red[buf][lane & 3][0]);
        float4 q0 = src[0], q1 = src[1], q2 = src[2];
        quad_reduce(q0); quad_reduce(q1); quad_reduce(q2);

        if (t == 0 && rr > 0)
            __builtin_nontemporal_store(q2.z, e_out + row - 1);   // prev row's e_curv

        const float mu  = q0.x * (1.0f / D);
        const float var = fmaxf(q0.y * (1.0f / D) - mu * mu, 0.0f);
        const float inv = rsqrtf(var + LN_EPS);
        const float dot[8] = {q0.z, q0.w, q1.x, q1.y, q1.z, q1.w, q2.x, q2.y};
        f2 c2[RANK];
        #pragma unroll
        for (int r = 0; r < RANK; ++r) {
            const float c = inv * (dot[r] - mu * vsum[r]);
            c2[r] = f2{c, c};
        }

        // ---- epilogue (packed)
        const f2 inv2  = f2{inv, inv};
        const f2 nmi2  = f2{-mu * inv, -mu * inv};
        const f2 neta2 = f2{-eta, -eta};
        f2 e2 = f2{0.f, 0.f};
        f2 ov[4];
        #pragma unroll
        for (int k = 0; k < 4; ++k) {
            const f2 hh = f2fma(h2[k], inv2, nmi2);
            f2 pr = c2[0] * vreg[k][0];
            #pragma unroll
            for (int r = 1; r < RANK; ++r) pr = f2fma(c2[r], vreg[k][r], pr);
            const f2 dl = hh - pr;
            e2 = f2fma(dl, dl, e2);
            const f2 sm = f2fma(neta2, dl, hh);
            ov[k] = f2fma(sm, gam[k], bet[k]);
        }
        ep = e2.x + e2.y;

        float* orow = out + row * (size_t)D;
        nt_store4(orow + c0, ov[0].x, ov[0].y, ov[1].x, ov[1].y);
        nt_store4(orow + c1, ov[2].x, ov[2].y, ov[3].x, ov[3].y);

        ha = na; hb = nb;
        if (rr + 2 < ROWS_PB) { na = pa; nb = pb; }
    }

    // ---- tail: e_curv of the last row
    ep = dpp_sum64(ep);
    if (lane == 63) red[0][wave][0] = ep;
    barrier_lds();
    if (t == 0) {
        const float e = red[0][0][0] + red[0][1][0] + red[0][2][0] + red[0][3][0];
        __builtin_nontemporal_store(e, e_out + row0 + ROWS_PB - 1);
    }
}

extern "C" void kernel_launch(void* const* d_in, const int* in_sizes, int n_in,
                              void* d_out, int out_size, void* d_ws, size_t ws_size,
                              hipStream_t stream) {
    const float* h     = (const float*)d_in[0];
    const float* gamma = (const float*)d_in[1];
    const float* beta  = (const float*)d_in[2];
    const float* V     = (const float*)d_in[3];
    const float* eta   = (const float*)d_in[4];
    float* out = (float*)d_out;

    const int d = in_sizes[1];                       // 2048
    const long long rows = in_sizes[0] / d;          // 16384
    float* e_out = out + (size_t)rows * d;

    dim3 grid((unsigned)(rows / ROWS_PB));
    lbonorm_kernel<<<grid, BLOCK, 0, stream>>>(h, gamma, beta, V, eta, out, e_out);
}